// Round 1
// baseline (374.122 us; speedup 1.0000x reference)
//
#include <hip/hip_runtime.h>
#include <hip/hip_bf16.h>

#define BATCH 64
#define SEQ   256
#define KDIM  1024
#define NDIM  4096
#define NCAT  16

#define BM 128
#define BN 128
#define BK 64
#define MT (SEQ/BM)              // 2 m-tiles per batch
#define NT (NDIM/BN)             // 32 n-tiles
#define TILES_PER_BATCH (MT*NT)  // 64
#define NBLOCKS (BATCH*TILES_PER_BATCH)  // 4096

typedef __attribute__((ext_vector_type(4))) float f32x4;
typedef __attribute__((ext_vector_type(2))) unsigned int u32x2;
typedef __attribute__((ext_vector_type(4))) unsigned int u32x4;
typedef __attribute__((ext_vector_type(8))) short bf16x8;

__device__ __forceinline__ unsigned short f2bf(float f) {
  __hip_bfloat16 h = __float2bfloat16(f);
  return __builtin_bit_cast(unsigned short, h);
}
__device__ __forceinline__ unsigned pack2(float lo, float hi) {
  return (unsigned)f2bf(lo) | ((unsigned)f2bf(hi) << 16);
}

__global__ __launch_bounds__(256, 2)
void csl_kernel(const float* __restrict__ x,
                const int*   __restrict__ cat_ids,
                const float* __restrict__ W,
                const float* __restrict__ bias,
                float* __restrict__ out)
{
  // A: [m][k] bf16, row=128B, swizzle byte ^= (m&7)<<4    (reads 2-way: free)
  // B: [n][k] bf16 (transposed from W), swizzle byte ^= ((n>>2)&7)<<4 (4-way r/w)
  __shared__ __align__(16) unsigned char sA[BM*BK*2];
  __shared__ __align__(16) unsigned char sB[BN*BK*2];
  __shared__ int s_cat[BATCH];

  const int tid  = threadIdx.x;
  const int lane = tid & 63;
  const int wid  = tid >> 6;

  if (tid < BATCH) s_cat[tid] = cat_ids[tid];
  __syncthreads();

  // ---- block remap: tiles ordered (category, n-tile, batch, m-tile) ----
  const int myc = s_cat[lane];
  int t_id = (int)blockIdx.x;
  int c = 0, base = 0, cc = 0;
  unsigned long long mask = 0ULL;
  for (c = 0; c < NCAT; ++c) {
    mask = __ballot(myc == c);
    cc = __popcll(mask);
    int sz = cc * TILES_PER_BATCH;
    if (t_id < base + sz) break;
    base += sz;
  }
  if (c >= NCAT) return;  // unreachable with valid cat_ids; memory safety
  const int idx    = t_id - base;
  const int per_nt = cc * MT;
  const int nt     = idx / per_nt;
  const int r      = idx % per_nt;
  const int want   = r >> 1;
  const int mt     = r & 1;
  unsigned long long mm = mask;
  for (int i = 0; i < want; ++i) mm &= (mm - 1);
  const int batch = __ffsll((long long)mm) - 1;
  const int cat   = c;

  const int m0 = mt * BM;
  const int n0 = nt * BN;

  const size_t x_base = ((size_t)batch * SEQ + m0) * KDIM;
  const size_t w_base = (size_t)cat * KDIM * NDIM + n0;

  f32x4 acc[4][4] = {};

  const int wr = (wid >> 1) * 64;   // wave row offset in tile
  const int wc = (wid & 1) * 64;    // wave col offset in tile

  for (int kt = 0; kt < KDIM / BK; ++kt) {
    const int k0 = kt * BK;

    // ---- global loads (fp32) ----
    f32x4 av[4][2];
#pragma unroll
    for (int s = 0; s < 4; ++s) {
      int seg  = tid + s * 256;          // 0..1023
      int arow = seg >> 3;               // 0..127
      int ak   = (seg & 7) << 3;         // 0,8,...,56
      const float* gp = x + x_base + (size_t)arow * KDIM + (size_t)(k0 + ak);
      av[s][0] = *(const f32x4*)gp;
      av[s][1] = *(const f32x4*)(gp + 4);
    }
    f32x4 bv[2][4];
#pragma unroll
    for (int s = 0; s < 2; ++s) {
      int u  = tid + s * 256;            // 0..511
      int nq = u & 31;                   // n/4
      int kq = u >> 5;                   // k/4
      const float* gp = W + w_base + (size_t)(k0 + kq * 4) * NDIM + (size_t)(nq * 4);
#pragma unroll
      for (int rr = 0; rr < 4; ++rr)
        bv[s][rr] = *(const f32x4*)(gp + (size_t)rr * NDIM);
    }

    __syncthreads();  // previous compute done reading LDS

    // ---- convert + LDS writes ----
#pragma unroll
    for (int s = 0; s < 4; ++s) {
      int seg  = tid + s * 256;
      int arow = seg >> 3;
      int akb  = (seg & 7) << 4;  // byte col
      unsigned byte = (unsigned)(arow * (BK * 2)) + ((unsigned)akb ^ (((unsigned)arow & 7u) << 4));
      u32x4 q;
      q[0] = pack2(av[s][0][0], av[s][0][1]);
      q[1] = pack2(av[s][0][2], av[s][0][3]);
      q[2] = pack2(av[s][1][0], av[s][1][1]);
      q[3] = pack2(av[s][1][2], av[s][1][3]);
      *(u32x4*)(sA + byte) = q;
    }
#pragma unroll
    for (int s = 0; s < 2; ++s) {
      int u  = tid + s * 256;
      int nq = u & 31;
      int kq = u >> 5;
      unsigned swz = ((unsigned)nq & 7u) << 4;
#pragma unroll
      for (int i = 0; i < 4; ++i) {
        int n = nq * 4 + i;
        unsigned byte = (unsigned)(n * (BK * 2)) + (((unsigned)(kq * 8)) ^ swz);
        u32x2 d;
        d[0] = pack2(bv[s][0][i], bv[s][1][i]);
        d[1] = pack2(bv[s][2][i], bv[s][3][i]);
        *(u32x2*)(sB + byte) = d;
      }
    }

    __syncthreads();  // tiles staged

    // ---- compute: 2 x (8 ds_read_b128 -> 16 MFMA) ----
#pragma unroll
    for (int kk = 0; kk < 2; ++kk) {
      const int kb = kk * 64 + ((lane >> 4) << 4);  // byte col in row
      bf16x8 af[4], bfr[4];
#pragma unroll
      for (int mi = 0; mi < 4; ++mi) {
        int row = wr + mi * 16 + (lane & 15);
        unsigned byte = (unsigned)(row * (BK * 2)) + ((unsigned)kb ^ (((unsigned)row & 7u) << 4));
        af[mi] = *(const bf16x8*)(sA + byte);
      }
#pragma unroll
      for (int ni = 0; ni < 4; ++ni) {
        int n = wc + ni * 16 + (lane & 15);
        unsigned byte = (unsigned)(n * (BK * 2)) + ((unsigned)kb ^ ((((unsigned)n >> 2) & 7u) << 4));
        bfr[ni] = *(const bf16x8*)(sB + byte);
      }
#pragma unroll
      for (int mi = 0; mi < 4; ++mi)
#pragma unroll
        for (int ni = 0; ni < 4; ++ni)
          acc[mi][ni] = __builtin_amdgcn_mfma_f32_16x16x32_bf16(af[mi], bfr[ni], acc[mi][ni], 0, 0, 0);
    }
  }

  // ---- epilogue: bias + store ----
  const int col_l = lane & 15;
  const int row_l = (lane >> 4) * 4;
#pragma unroll
  for (int mi = 0; mi < 4; ++mi) {
#pragma unroll
    for (int ni = 0; ni < 4; ++ni) {
      int gr = m0 + wr + mi * 16 + row_l;
      int gc = n0 + wc + ni * 16 + col_l;
      float bvl = bias[(size_t)cat * NDIM + gc];
      f32x4 v = acc[mi][ni];
      size_t o = ((size_t)batch * SEQ + gr) * NDIM + gc;
      out[o]            = v[0] + bvl;
      out[o + NDIM]     = v[1] + bvl;
      out[o + 2 * NDIM] = v[2] + bvl;
      out[o + 3 * NDIM] = v[3] + bvl;
    }
  }
}

extern "C" void kernel_launch(void* const* d_in, const int* in_sizes, int n_in,
                              void* d_out, int out_size, void* d_ws, size_t ws_size,
                              hipStream_t stream) {
  const float* x        = (const float*)d_in[0];
  const int*   cat_ids  = (const int*)d_in[1];
  const float* W        = (const float*)d_in[2];
  const float* bias     = (const float*)d_in[3];
  float*       out      = (float*)d_out;
  (void)in_sizes; (void)n_in; (void)out_size; (void)d_ws; (void)ws_size;
  hipLaunchKernelGGL(csl_kernel, dim3(NBLOCKS), dim3(256), 0, stream,
                     x, cat_ids, W, bias, out);
}

// Round 2
// 299.834 us; speedup vs baseline: 1.2478x; 1.2478x over previous
//
#include <hip/hip_runtime.h>
#include <hip/hip_bf16.h>
#include <stdint.h>

#define BATCH 64
#define SEQ   256
#define KDIM  1024
#define NDIM  4096
#define NCAT  16

#define BM 128
#define BN 128
#define BK 64
#define MT (SEQ/BM)              // 2
#define NT (NDIM/BN)             // 32
#define TILES_PER_BATCH (MT*NT)  // 64
#define NBLOCKS (BATCH*TILES_PER_BATCH)  // 4096

typedef __attribute__((ext_vector_type(4))) float f32x4;
typedef __attribute__((ext_vector_type(2))) unsigned int u32x2;
typedef __attribute__((ext_vector_type(4))) unsigned int u32x4;
typedef __attribute__((ext_vector_type(8))) short bf16x8;

__device__ __forceinline__ unsigned short f2bf(float f) {
  __hip_bfloat16 h = __float2bfloat16(f);
  return __builtin_bit_cast(unsigned short, h);
}
__device__ __forceinline__ unsigned pack2(float lo, float hi) {
  return (unsigned)f2bf(lo) | ((unsigned)f2bf(hi) << 16);
}

__device__ __forceinline__ void gload16(const void* g, void* l) {
  __builtin_amdgcn_global_load_lds(
      (const __attribute__((address_space(1))) unsigned int*)g,
      (__attribute__((address_space(3))) unsigned int*)l, 16, 0, 0);
}

// ---------------- pass 1a: x fp32 -> bf16 ----------------
__global__ void cvt_x_kernel(const float* __restrict__ x,
                             unsigned short* __restrict__ xb, int n8) {
  int i = blockIdx.x * blockDim.x + threadIdx.x;
  const int stride = gridDim.x * blockDim.x;
  for (; i < n8; i += stride) {
    f32x4 a = ((const f32x4*)x)[2 * i];
    f32x4 b = ((const f32x4*)x)[2 * i + 1];
    u32x4 q;
    q[0] = pack2(a[0], a[1]); q[1] = pack2(a[2], a[3]);
    q[2] = pack2(b[0], b[1]); q[3] = pack2(b[2], b[3]);
    ((u32x4*)xb)[i] = q;
  }
}

// ---------------- pass 1b: W fp32 [cat][k][n] -> bf16 transposed [cat][n][k] ----------------
__global__ void cvt_w_kernel(const float* __restrict__ W,
                             unsigned short* __restrict__ Wt) {
  __shared__ float ls[64][65];   // odd pad: 2-way (free) on both LDS phases
  const int bid = blockIdx.x;                 // 16384 blocks
  const int cat = bid >> 10;
  const int rem = bid & 1023;
  const int kt  = rem >> 6;                   // 0..15  (k-tile of 64)
  const int ntl = rem & 63;                   // 0..63  (n-tile of 64)
  const int tid = threadIdx.x;

  const float* src = W + (size_t)cat * KDIM * NDIM + (size_t)(kt * 64) * NDIM + ntl * 64;
  const int kl = tid >> 4;            // 0..15
  const int nl = (tid & 15) * 4;
#pragma unroll
  for (int i = 0; i < 4; ++i) {
    f32x4 v = *(const f32x4*)(src + (size_t)(kl + i * 16) * NDIM + nl);
    ls[kl + i * 16][nl + 0] = v[0];
    ls[kl + i * 16][nl + 1] = v[1];
    ls[kl + i * 16][nl + 2] = v[2];
    ls[kl + i * 16][nl + 3] = v[3];
  }
  __syncthreads();
  const int n  = tid >> 2;            // 0..63
  const int k2 = (tid & 3) * 16;      // 0,16,32,48
  u32x4 q0, q1;
#pragma unroll
  for (int j = 0; j < 4; ++j) q0[j] = pack2(ls[k2 + 2 * j][n],     ls[k2 + 2 * j + 1][n]);
#pragma unroll
  for (int j = 0; j < 4; ++j) q1[j] = pack2(ls[k2 + 8 + 2 * j][n], ls[k2 + 9 + 2 * j][n]);
  unsigned short* dst = Wt + (size_t)cat * NDIM * KDIM + (size_t)(ntl * 64 + n) * KDIM + kt * 64 + k2;
  *(u32x4*)dst       = q0;
  *(u32x4*)(dst + 8) = q1;
}

// ---------------- pass 2: category-gathered bf16 GEMM (m97 structure) ----------------
__global__ __launch_bounds__(256, 4)
void csl_gemm(const unsigned short* __restrict__ xb,
              const unsigned short* __restrict__ Wt,
              const int*   __restrict__ cat_ids,
              const float* __restrict__ bias,
              float* __restrict__ out)
{
  __shared__ __align__(16) unsigned char sA[BM * BK * 2];  // [m][k] linear (gload_lds order)
  __shared__ __align__(16) unsigned char sB[BN * BK * 2];  // [n][k] linear
  __shared__ int s_cat[BATCH];

  const int tid  = threadIdx.x;
  const int lane = tid & 63;
  const int wid  = tid >> 6;

  if (tid < BATCH) s_cat[tid] = cat_ids[tid];
  __syncthreads();

  // T1: bijective XCD swizzle (4096 % 8 == 0) so logically-consecutive tiles share an L2
  const int bid  = (int)blockIdx.x;
  const int t_id = (bid & 7) * (NBLOCKS / 8) + (bid >> 3);

  // category-sorted decode: tiles ordered (cat, n-tile, batch, m-tile)
  const int myc = s_cat[lane];
  int c = 0, base = 0, cc = 0;
  unsigned long long mask = 0ULL;
  for (c = 0; c < NCAT; ++c) {
    mask = __ballot(myc == c);
    cc = __popcll(mask);
    int sz = cc * TILES_PER_BATCH;
    if (t_id < base + sz) break;
    base += sz;
  }
  if (c >= NCAT) return;
  const int idx    = t_id - base;
  const int per_nt = cc * MT;
  const int nt     = idx / per_nt;
  const int r      = idx % per_nt;
  const int want   = r >> 1;
  const int mt     = r & 1;
  unsigned long long mm = mask;
  for (int i = 0; i < want; ++i) mm &= (mm - 1);
  const int batch = __ffsll((long long)mm) - 1;
  const int cat   = c;

  const int m0 = mt * BM;
  const int n0 = nt * BN;

  const size_t xa = ((size_t)batch * SEQ + m0) * KDIM;       // bf16 elem offset
  const size_t wa = ((size_t)cat * NDIM + n0) * KDIM;        // Wt is [cat][n][k]

  const int srow = tid >> 3;          // staging row within 32-row group
  const int skq  = tid & 7;           // 8-elem k chunk
  const unsigned ldsb = (unsigned)(wid * 1024);

  f32x4 acc[4][4] = {};
  const int wr   = (wid >> 1) * 64;
  const int wc   = (wid & 1) * 64;
  const int mcol = lane & 15;
  const int kq16 = (lane >> 4) * 16;  // byte offset of k-quarter

  for (int kt = 0; kt < KDIM / BK; ++kt) {
    const int k0 = kt * BK;
    __syncthreads();                  // previous compute done reading LDS
#pragma unroll
    for (int s = 0; s < 4; ++s) {
      const unsigned short* gp = xb + xa + (size_t)(s * 32 + srow) * KDIM + (k0 + skq * 8);
      gload16(gp, sA + s * 4096 + ldsb);
    }
#pragma unroll
    for (int s = 0; s < 4; ++s) {
      const unsigned short* gp = Wt + wa + (size_t)(s * 32 + srow) * KDIM + (k0 + skq * 8);
      gload16(gp, sB + s * 4096 + ldsb);
    }
    __syncthreads();                  // drains vmcnt: tiles staged
#pragma unroll
    for (int kk = 0; kk < 2; ++kk) {
      const int kb = kk * 64 + kq16;
      bf16x8 af[4], bfr[4];
#pragma unroll
      for (int mi = 0; mi < 4; ++mi)
        af[mi] = *(const bf16x8*)(sA + (unsigned)((wr + mi * 16 + mcol) * 128 + kb));
#pragma unroll
      for (int ni = 0; ni < 4; ++ni)
        bfr[ni] = *(const bf16x8*)(sB + (unsigned)((wc + ni * 16 + mcol) * 128 + kb));
#pragma unroll
      for (int mi = 0; mi < 4; ++mi)
#pragma unroll
        for (int ni = 0; ni < 4; ++ni)
          acc[mi][ni] = __builtin_amdgcn_mfma_f32_16x16x32_bf16(af[mi], bfr[ni], acc[mi][ni], 0, 0, 0);
    }
  }

  // epilogue: bias + fp32 store (layout verified in R1)
  const int col_l = lane & 15;
  const int row_l = (lane >> 4) * 4;
#pragma unroll
  for (int mi = 0; mi < 4; ++mi) {
#pragma unroll
    for (int ni = 0; ni < 4; ++ni) {
      int gr = m0 + wr + mi * 16 + row_l;
      int gc = n0 + wc + ni * 16 + col_l;
      float bvl = bias[(size_t)cat * NDIM + gc];
      f32x4 v = acc[mi][ni];
      size_t o = ((size_t)batch * SEQ + gr) * NDIM + gc;
      out[o]            = v[0] + bvl;
      out[o + NDIM]     = v[1] + bvl;
      out[o + 2 * NDIM] = v[2] + bvl;
      out[o + 3 * NDIM] = v[3] + bvl;
    }
  }
}

// ---------------- fallback: verified R1 kernel (used only if ws too small) ----------------
__global__ __launch_bounds__(256, 2)
void csl_fallback(const float* __restrict__ x,
                  const int*   __restrict__ cat_ids,
                  const float* __restrict__ W,
                  const float* __restrict__ bias,
                  float* __restrict__ out)
{
  __shared__ __align__(16) unsigned char sA[BM * BK * 2];
  __shared__ __align__(16) unsigned char sB[BN * BK * 2];
  __shared__ int s_cat[BATCH];

  const int tid  = threadIdx.x;
  const int lane = tid & 63;
  const int wid  = tid >> 6;

  if (tid < BATCH) s_cat[tid] = cat_ids[tid];
  __syncthreads();

  const int myc = s_cat[lane];
  int t_id = (int)blockIdx.x;
  int c = 0, base = 0, cc = 0;
  unsigned long long mask = 0ULL;
  for (c = 0; c < NCAT; ++c) {
    mask = __ballot(myc == c);
    cc = __popcll(mask);
    int sz = cc * TILES_PER_BATCH;
    if (t_id < base + sz) break;
    base += sz;
  }
  if (c >= NCAT) return;
  const int idx    = t_id - base;
  const int per_nt = cc * MT;
  const int nt     = idx / per_nt;
  const int r      = idx % per_nt;
  const int want   = r >> 1;
  const int mt     = r & 1;
  unsigned long long mm = mask;
  for (int i = 0; i < want; ++i) mm &= (mm - 1);
  const int batch = __ffsll((long long)mm) - 1;
  const int cat   = c;

  const int m0 = mt * BM;
  const int n0 = nt * BN;

  const size_t x_base = ((size_t)batch * SEQ + m0) * KDIM;
  const size_t w_base = (size_t)cat * KDIM * NDIM + n0;

  f32x4 acc[4][4] = {};
  const int wr = (wid >> 1) * 64;
  const int wc = (wid & 1) * 64;

  for (int kt = 0; kt < KDIM / BK; ++kt) {
    const int k0 = kt * BK;
    f32x4 av[4][2];
#pragma unroll
    for (int s = 0; s < 4; ++s) {
      int seg  = tid + s * 256;
      int arow = seg >> 3;
      int ak   = (seg & 7) << 3;
      const float* gp = x + x_base + (size_t)arow * KDIM + (size_t)(k0 + ak);
      av[s][0] = *(const f32x4*)gp;
      av[s][1] = *(const f32x4*)(gp + 4);
    }
    f32x4 bv[2][4];
#pragma unroll
    for (int s = 0; s < 2; ++s) {
      int u  = tid + s * 256;
      int nq = u & 31;
      int kq = u >> 5;
      const float* gp = W + w_base + (size_t)(k0 + kq * 4) * NDIM + (size_t)(nq * 4);
#pragma unroll
      for (int rr = 0; rr < 4; ++rr)
        bv[s][rr] = *(const f32x4*)(gp + (size_t)rr * NDIM);
    }
    __syncthreads();
#pragma unroll
    for (int s = 0; s < 4; ++s) {
      int seg  = tid + s * 256;
      int arow = seg >> 3;
      int akb  = (seg & 7) << 4;
      unsigned byte = (unsigned)(arow * (BK * 2)) + ((unsigned)akb ^ (((unsigned)arow & 7u) << 4));
      u32x4 q;
      q[0] = pack2(av[s][0][0], av[s][0][1]);
      q[1] = pack2(av[s][0][2], av[s][0][3]);
      q[2] = pack2(av[s][1][0], av[s][1][1]);
      q[3] = pack2(av[s][1][2], av[s][1][3]);
      *(u32x4*)(sA + byte) = q;
    }
#pragma unroll
    for (int s = 0; s < 2; ++s) {
      int u  = tid + s * 256;
      int nq = u & 31;
      int kq = u >> 5;
      unsigned swz = ((unsigned)nq & 7u) << 4;
#pragma unroll
      for (int i = 0; i < 4; ++i) {
        int n = nq * 4 + i;
        unsigned byte = (unsigned)(n * (BK * 2)) + (((unsigned)(kq * 8)) ^ swz);
        u32x2 d;
        d[0] = pack2(bv[s][0][i], bv[s][1][i]);
        d[1] = pack2(bv[s][2][i], bv[s][3][i]);
        *(u32x2*)(sB + byte) = d;
      }
    }
    __syncthreads();
#pragma unroll
    for (int kk = 0; kk < 2; ++kk) {
      const int kb = kk * 64 + ((lane >> 4) << 4);
      bf16x8 af[4], bfr[4];
#pragma unroll
      for (int mi = 0; mi < 4; ++mi) {
        int row = wr + mi * 16 + (lane & 15);
        unsigned byte = (unsigned)(row * (BK * 2)) + ((unsigned)kb ^ (((unsigned)row & 7u) << 4));
        af[mi] = *(const bf16x8*)(sA + byte);
      }
#pragma unroll
      for (int ni = 0; ni < 4; ++ni) {
        int n = wc + ni * 16 + (lane & 15);
        unsigned byte = (unsigned)(n * (BK * 2)) + ((unsigned)kb ^ ((((unsigned)n >> 2) & 7u) << 4));
        bfr[ni] = *(const bf16x8*)(sB + byte);
      }
#pragma unroll
      for (int mi = 0; mi < 4; ++mi)
#pragma unroll
        for (int ni = 0; ni < 4; ++ni)
          acc[mi][ni] = __builtin_amdgcn_mfma_f32_16x16x32_bf16(af[mi], bfr[ni], acc[mi][ni], 0, 0, 0);
    }
  }

  const int col_l = lane & 15;
  const int row_l = (lane >> 4) * 4;
#pragma unroll
  for (int mi = 0; mi < 4; ++mi) {
#pragma unroll
    for (int ni = 0; ni < 4; ++ni) {
      int gr = m0 + wr + mi * 16 + row_l;
      int gc = n0 + wc + ni * 16 + col_l;
      float bvl = bias[(size_t)cat * NDIM + gc];
      f32x4 v = acc[mi][ni];
      size_t o = ((size_t)batch * SEQ + gr) * NDIM + gc;
      out[o]            = v[0] + bvl;
      out[o + NDIM]     = v[1] + bvl;
      out[o + 2 * NDIM] = v[2] + bvl;
      out[o + 3 * NDIM] = v[3] + bvl;
    }
  }
}

extern "C" void kernel_launch(void* const* d_in, const int* in_sizes, int n_in,
                              void* d_out, int out_size, void* d_ws, size_t ws_size,
                              hipStream_t stream) {
  const float* x       = (const float*)d_in[0];
  const int*   cat_ids = (const int*)d_in[1];
  const float* W       = (const float*)d_in[2];
  const float* bias    = (const float*)d_in[3];
  float*       out     = (float*)d_out;
  (void)in_sizes; (void)n_in; (void)out_size;

  const size_t wt_elems = (size_t)NCAT * NDIM * KDIM;            // 67.1M bf16
  const size_t xb_elems = (size_t)BATCH * SEQ * KDIM;            // 16.8M bf16
  const size_t need = (wt_elems + xb_elems) * sizeof(unsigned short);  // ~168 MB

  if (ws_size >= need) {
    unsigned short* Wt = (unsigned short*)d_ws;
    unsigned short* xb = Wt + wt_elems;
    hipLaunchKernelGGL(cvt_x_kernel, dim3(2048), dim3(256), 0, stream,
                       x, xb, (int)(xb_elems / 8));
    hipLaunchKernelGGL(cvt_w_kernel, dim3(NCAT * (KDIM / 64) * (NDIM / 64)), dim3(256), 0, stream,
                       W, Wt);
    hipLaunchKernelGGL(csl_gemm, dim3(NBLOCKS), dim3(256), 0, stream,
                       xb, Wt, cat_ids, bias, out);
  } else {
    hipLaunchKernelGGL(csl_fallback, dim3(NBLOCKS), dim3(256), 0, stream,
                       x, cat_ids, W, bias, out);
  }
}